// Round 3
// baseline (64.231 us; speedup 1.0000x reference)
//
#include <hip/hip_runtime.h>
#include <hip/hip_bf16.h>

// x[4096,2048] f32, w[2048,2048] f32, bias[2048] f32, indices = permutation of
// K axis applied to BOTH operands -> cancels out of the einsum; unused.
#define M_DIM 4096
#define N_DIM 2048
#define K_DIM 2048

// 256x128 tile, BK=64, 8 waves (4M x 2N), 64x64 per wave.
// Grid = 16 x 16 = 256 blocks = 1 block/CU.
#define BM 256
#define BN 128
#define BK 64
#define NT (K_DIM / BK)      // 32 K-tiles
#define A_TILE (BM * BK)     // 16384 elems = 32 KiB
#define B_TILE (BN * BK)     // 8192 elems  = 16 KiB

typedef __bf16 bf16x8 __attribute__((ext_vector_type(8)));
typedef float f32x4 __attribute__((ext_vector_type(4)));
typedef unsigned short u16x8 __attribute__((ext_vector_type(8)));

__device__ __forceinline__ unsigned short f32_to_bf16_rne(float f) {
  unsigned int u = __float_as_uint(f);
  u += 0x7fffu + ((u >> 16) & 1u);
  return (unsigned short)(u >> 16);
}

// ---- merged f32 -> bf16 conversion for x and w ----
__global__ __launch_bounds__(256) void cvt_both(
    const float* __restrict__ x, const float* __restrict__ w,
    unsigned short* __restrict__ out, int xn8, int totn8) {
  int i = blockIdx.x * 256 + threadIdx.x;
  if (i >= totn8) return;
  const float* src = (i < xn8) ? (x + (size_t)i * 8)
                               : (w + (size_t)(i - xn8) * 8);
  f32x4 a = reinterpret_cast<const f32x4*>(src)[0];
  f32x4 b = reinterpret_cast<const f32x4*>(src)[1];
  u16x8 o;
  o[0] = f32_to_bf16_rne(a[0]); o[1] = f32_to_bf16_rne(a[1]);
  o[2] = f32_to_bf16_rne(a[2]); o[3] = f32_to_bf16_rne(a[3]);
  o[4] = f32_to_bf16_rne(b[0]); o[5] = f32_to_bf16_rne(b[1]);
  o[6] = f32_to_bf16_rne(b[2]); o[7] = f32_to_bf16_rne(b[3]);
  reinterpret_cast<u16x8*>(out)[i] = o;
}

__device__ __forceinline__ void gload_lds16(const unsigned short* g, unsigned short* l) {
  __builtin_amdgcn_global_load_lds(
      (const __attribute__((address_space(1))) unsigned int*)g,
      (__attribute__((address_space(3))) unsigned int*)l, 16, 0, 0);
}

#define LD8(p) (*reinterpret_cast<const bf16x8*>(p))

// Triple-buffered, counted-vmcnt, swizzled-LDS, 2-phase-per-K-tile bf16 GEMM.
// C[M][N] = A[M][K] * B[N][K]^T + bias.
// Swizzle (rule 21): 16B chunk s within a row holds global chunk s ^ (row&7);
// reads XOR the same term. R2 measured SQ_LDS_BANK_CONFLICT = 0.
__global__ __launch_bounds__(512, 2) void gemm_8w(
    const unsigned short* __restrict__ A,   // [M][K] bf16 bits
    const unsigned short* __restrict__ B,   // [N][K] bf16 bits
    const float* __restrict__ bias,         // [N]
    float* __restrict__ C) {                // [M][N] f32
  __shared__ unsigned short As[3 * A_TILE]; // 96 KiB
  __shared__ unsigned short Bs[3 * B_TILE]; // 48 KiB

  const int tid  = threadIdx.x;
  const int lane = tid & 63;
  const int wave = tid >> 6;   // 0..7
  const int wr   = wave >> 1;  // 0..3 (M)
  const int wc   = wave & 1;   // 0..1 (N)
  const int bn   = blockIdx.x; // 0..15
  const int bm   = blockIdx.y; // 0..15

  // ---- staging addresses: 512 thr x 16B = 64 rows x 128B per issue ----
  const int srow   = tid >> 3;
  const int schunk = (tid & 7) ^ (srow & 7);
  const unsigned short* Ag[4];
  const unsigned short* Bg[2];
#pragma unroll
  for (int j = 0; j < 4; ++j)
    Ag[j] = A + (size_t)(bm * BM + j * 64 + srow) * K_DIM + schunk * 8;
#pragma unroll
  for (int j = 0; j < 2; ++j)
    Bg[j] = B + (size_t)(bn * BN + j * 64 + srow) * K_DIM + schunk * 8;

#define STAGE_A01(buf, k0) do { \
    unsigned short* _d = &As[(buf) * A_TILE + tid * 8]; \
    gload_lds16(Ag[0] + (k0), _d); \
    gload_lds16(Ag[1] + (k0), _d + 4096); \
  } while (0)
#define STAGE_A23(buf, k0) do { \
    unsigned short* _d = &As[(buf) * A_TILE + 8192 + tid * 8]; \
    gload_lds16(Ag[2] + (k0), _d); \
    gload_lds16(Ag[3] + (k0), _d + 4096); \
  } while (0)
#define STAGE_B01(buf, k0) do { \
    unsigned short* _d = &Bs[(buf) * B_TILE + tid * 8]; \
    gload_lds16(Bg[0] + (k0), _d); \
    gload_lds16(Bg[1] + (k0), _d + 4096); \
  } while (0)

  // ---- ds_read offsets (elements): fragment row (..+fr), k = kk*32 + qq*8.
  // Logical 16B chunk c = kk*4 + qq; swizzled slot = c ^ (fr&7).
  const int fr = lane & 15;
  const int qq = lane >> 4;
  const int xr = fr & 7;
  int aoff[4][2], boff[4][2];
#pragma unroll
  for (int mi = 0; mi < 4; ++mi)
#pragma unroll
    for (int kk = 0; kk < 2; ++kk)
      aoff[mi][kk] = ((wr * 64 + mi * 16 + fr) * 8 + ((kk * 4 + qq) ^ xr)) * 8;
#pragma unroll
  for (int ni = 0; ni < 4; ++ni)
#pragma unroll
    for (int kk = 0; kk < 2; ++kk)
      boff[ni][kk] = ((wc * 64 + ni * 16 + fr) * 8 + ((kk * 4 + qq) ^ xr)) * 8;

  const f32x4 z = {0.f, 0.f, 0.f, 0.f};
  f32x4 acc[4][4];
#pragma unroll
  for (int i = 0; i < 4; ++i)
#pragma unroll
    for (int j = 0; j < 4; ++j) acc[i][j] = z;

#define MFMA_ROW(mi, av) do { \
    acc[mi][0] = __builtin_amdgcn_mfma_f32_16x16x32_bf16(av, bv0, acc[mi][0], 0, 0, 0); \
    acc[mi][1] = __builtin_amdgcn_mfma_f32_16x16x32_bf16(av, bv1, acc[mi][1], 0, 0, 0); \
    acc[mi][2] = __builtin_amdgcn_mfma_f32_16x16x32_bf16(av, bv2, acc[mi][2], 0, 0, 0); \
    acc[mi][3] = __builtin_amdgcn_mfma_f32_16x16x32_bf16(av, bv3, acc[mi][3], 0, 0, 0); \
  } while (0)

  // W: 6 -> vmcnt(6) (steady state: stage(t+2)'s 6 loads stay in flight),
  //    0 -> vmcnt(0) (drain), -1 -> none.
#define TRAIL_WAIT(W) do { \
    if ((W) == 6)      asm volatile("s_waitcnt vmcnt(6)" ::: "memory"); \
    else if ((W) == 0) asm volatile("s_waitcnt vmcnt(0)" ::: "memory"); \
  } while (0)

  // One K-tile = 2 phases. Per phase (m201 cadence):
  //   {8 x ds_read_b128 ; 2-4 x global_load_lds ; s_barrier ; lgkmcnt(0) ;
  //    sched_barrier(0) [rule 18] ; setprio(1) ; 16 MFMA ; setprio(0) ;
  //    [trailing vmcnt once per tile] ; s_barrier}
#define TILE(t_, STG, W) do { \
    const int b_ = (t_) % 3; \
    const unsigned short* Asb = &As[b_ * A_TILE]; \
    const unsigned short* Bsb = &Bs[b_ * B_TILE]; \
    const int sb_ = ((t_) + 2) % 3; \
    const int sk0_ = ((t_) + 2) * BK; \
    bf16x8 av0, av1, av2, av3, bv0, bv1, bv2, bv3; \
    /* ---- phase A (kk0) ---- */ \
    bv0 = LD8(Bsb + boff[0][0]); bv1 = LD8(Bsb + boff[1][0]); \
    bv2 = LD8(Bsb + boff[2][0]); bv3 = LD8(Bsb + boff[3][0]); \
    av0 = LD8(Asb + aoff[0][0]); av1 = LD8(Asb + aoff[1][0]); \
    av2 = LD8(Asb + aoff[2][0]); av3 = LD8(Asb + aoff[3][0]); \
    if (STG) { STAGE_A01(sb_, sk0_); STAGE_A23(sb_, sk0_); } \
    __builtin_amdgcn_s_barrier(); \
    asm volatile("s_waitcnt lgkmcnt(0)" ::: "memory"); \
    __builtin_amdgcn_sched_barrier(0); \
    __builtin_amdgcn_s_setprio(1); \
    MFMA_ROW(0, av0); MFMA_ROW(1, av1); MFMA_ROW(2, av2); MFMA_ROW(3, av3); \
    __builtin_amdgcn_s_setprio(0); \
    __builtin_amdgcn_s_barrier(); \
    /* ---- phase B (kk1) ---- */ \
    bv0 = LD8(Bsb + boff[0][1]); bv1 = LD8(Bsb + boff[1][1]); \
    bv2 = LD8(Bsb + boff[2][1]); bv3 = LD8(Bsb + boff[3][1]); \
    av0 = LD8(Asb + aoff[0][1]); av1 = LD8(Asb + aoff[1][1]); \
    av2 = LD8(Asb + aoff[2][1]); av3 = LD8(Asb + aoff[3][1]); \
    if (STG) STAGE_B01(sb_, sk0_); \
    __builtin_amdgcn_s_barrier(); \
    asm volatile("s_waitcnt lgkmcnt(0)" ::: "memory"); \
    __builtin_amdgcn_sched_barrier(0); \
    __builtin_amdgcn_s_setprio(1); \
    MFMA_ROW(0, av0); MFMA_ROW(1, av1); MFMA_ROW(2, av2); MFMA_ROW(3, av3); \
    __builtin_amdgcn_s_setprio(0); \
    TRAIL_WAIT(W); \
    __builtin_amdgcn_s_barrier(); \
  } while (0)

  // prologue: stage tiles 0 and 1; wait for tile 0 (tile 1's 6 may remain).
  STAGE_A01(0, 0); STAGE_A23(0, 0); STAGE_B01(0, 0);
  STAGE_A01(1, BK); STAGE_A23(1, BK); STAGE_B01(1, BK);
  asm volatile("s_waitcnt vmcnt(6)" ::: "memory");
  __builtin_amdgcn_s_barrier();
  __builtin_amdgcn_sched_barrier(0);

#pragma unroll 1
  for (int t = 0; t < NT - 2; ++t) {
    TILE(t, 1, 6);
  }
  TILE(NT - 2, 0, 0);   // drain: tile NT-1's loads must land
  TILE(NT - 1, 0, -1);  // last tile: no staging, no wait

  // ---- epilogue: C/D layout col = lane&15, row = (lane>>4)*4 + r ----
  const int orow0 = bm * BM + wr * 64 + qq * 4;
  const int ocol0 = bn * BN + wc * 64 + fr;
#pragma unroll
  for (int ni = 0; ni < 4; ++ni) {
    const int col = ocol0 + ni * 16;
    const float bv = bias[col];
#pragma unroll
    for (int mi = 0; mi < 4; ++mi) {
      const int row = orow0 + mi * 16;
#pragma unroll
      for (int r = 0; r < 4; ++r)
        C[(size_t)(row + r) * N_DIM + col] = acc[mi][ni][r] + bv;
    }
  }
#undef TILE
#undef TRAIL_WAIT
#undef MFMA_ROW
#undef STAGE_A01
#undef STAGE_A23
#undef STAGE_B01
}

// ---- safety fallback ----
__global__ __launch_bounds__(256) void gemm_f32_naive(
    const float* __restrict__ X, const float* __restrict__ W,
    const float* __restrict__ bias, float* __restrict__ C) {
  int o = blockIdx.x * 256 + threadIdx.x;
  if (o >= M_DIM * N_DIM) return;
  int m = o / N_DIM, n = o % N_DIM;
  const float* xr = X + (size_t)m * K_DIM;
  const float* wr = W + (size_t)n * K_DIM;
  float s = 0.f;
  for (int k = 0; k < K_DIM; ++k) s += xr[k] * wr[k];
  C[o] = s + bias[n];
}

extern "C" void kernel_launch(void* const* d_in, const int* in_sizes, int n_in,
                              void* d_out, int out_size, void* d_ws, size_t ws_size,
                              hipStream_t stream) {
  const float* x    = (const float*)d_in[0];
  const float* w    = (const float*)d_in[1];
  const float* bias = (const float*)d_in[2];
  float* out = (float*)d_out;

  const size_t x_elems = (size_t)M_DIM * K_DIM;
  const size_t w_elems = (size_t)N_DIM * K_DIM;
  const size_t need = (x_elems + w_elems) * sizeof(unsigned short);

  if (ws_size < need) {
    gemm_f32_naive<<<(M_DIM * N_DIM + 255) / 256, 256, 0, stream>>>(x, w, bias, out);
    return;
  }

  unsigned short* xb = (unsigned short*)d_ws;
  unsigned short* wb = xb + x_elems;

  const int xn8 = (int)(x_elems / 8);
  const int totn8 = (int)((x_elems + w_elems) / 8);
  cvt_both<<<(totn8 + 255) / 256, 256, 0, stream>>>(x, w, xb, xn8, totn8);

  dim3 grid(N_DIM / BN, M_DIM / BM);  // (16, 16) = 256 blocks, 1/CU
  gemm_8w<<<grid, 512, 0, stream>>>(xb, wb, bias, out);
}

// Round 4
// 55.523 us; speedup vs baseline: 1.1568x; 1.1568x over previous
//
#include <hip/hip_runtime.h>
#include <hip/hip_bf16.h>

// x[4096,2048] f32, w[2048,2048] f32, bias[2048] f32, indices = permutation of
// K axis applied to BOTH operands -> cancels out of the einsum; unused.
#define M_DIM 4096
#define N_DIM 2048
#define K_DIM 2048

// 256x128 tile, BK=64, 8 waves (4M x 2N), 64x64 per wave.
// Grid = 16 x 16 = 256 blocks = 1 block/CU.
#define BM 256
#define BN 128
#define BK 64
#define NT (K_DIM / BK)      // 32 K-tiles
#define A_TILE (BM * BK)     // 16384 elems = 32 KiB
#define B_TILE (BN * BK)     // 8192 elems  = 16 KiB

typedef __bf16 bf16x8 __attribute__((ext_vector_type(8)));
typedef float f32x4 __attribute__((ext_vector_type(4)));
typedef unsigned short u16x8 __attribute__((ext_vector_type(8)));

__device__ __forceinline__ unsigned short f32_to_bf16_rne(float f) {
  unsigned int u = __float_as_uint(f);
  u += 0x7fffu + ((u >> 16) & 1u);
  return (unsigned short)(u >> 16);
}

// ---- merged f32 -> bf16 conversion for x and w ----
__global__ __launch_bounds__(256) void cvt_both(
    const float* __restrict__ x, const float* __restrict__ w,
    unsigned short* __restrict__ out, int xn8, int totn8) {
  int i = blockIdx.x * 256 + threadIdx.x;
  if (i >= totn8) return;
  const float* src = (i < xn8) ? (x + (size_t)i * 8)
                               : (w + (size_t)(i - xn8) * 8);
  f32x4 a = reinterpret_cast<const f32x4*>(src)[0];
  f32x4 b = reinterpret_cast<const f32x4*>(src)[1];
  u16x8 o;
  o[0] = f32_to_bf16_rne(a[0]); o[1] = f32_to_bf16_rne(a[1]);
  o[2] = f32_to_bf16_rne(a[2]); o[3] = f32_to_bf16_rne(a[3]);
  o[4] = f32_to_bf16_rne(b[0]); o[5] = f32_to_bf16_rne(b[1]);
  o[6] = f32_to_bf16_rne(b[2]); o[7] = f32_to_bf16_rne(b[3]);
  reinterpret_cast<u16x8*>(out)[i] = o;
}

__device__ __forceinline__ void gload_lds16(const unsigned short* g, unsigned short* l) {
  __builtin_amdgcn_global_load_lds(
      (const __attribute__((address_space(1))) unsigned int*)g,
      (__attribute__((address_space(3))) unsigned int*)l, 16, 0, 0);
}

#define LD8(p) (*reinterpret_cast<const bf16x8*>(p))
#define VMWAIT_(n) asm volatile("s_waitcnt vmcnt(" #n ")" ::: "memory")
#define VMWAIT(n) VMWAIT_(n)
#define SBAR() __builtin_amdgcn_s_barrier()
#define SCHED() __builtin_amdgcn_sched_barrier(0)

// Derived-waits pipelined bf16 GEMM. C[M][N] = A[M][K] * B[N][K]^T + bias.
// Register subtiles are read ONE PHASE AHEAD (phase A reads B-regs(t),
// phase B reads A-regs(t+1)), so the wait before each MFMA cluster is a
// counted, already-satisfied lgkmcnt (compiler-emitted) and the LDS pipe
// overlaps the MFMA pipe. Triple LDS buffer, stage distance 2 tiles,
// vmcnt(6) once per tile (never drain). Swizzle as R2 (0 conflicts).
__global__ __launch_bounds__(512, 2) void gemm_8w(
    const unsigned short* __restrict__ A,   // [M][K] bf16 bits
    const unsigned short* __restrict__ B,   // [N][K] bf16 bits
    const float* __restrict__ bias,         // [N]
    float* __restrict__ C) {                // [M][N] f32
  __shared__ unsigned short As[3 * A_TILE]; // 96 KiB
  __shared__ unsigned short Bs[3 * B_TILE]; // 48 KiB

  const int tid  = threadIdx.x;
  const int lane = tid & 63;
  const int wave = tid >> 6;   // 0..7
  const int wr   = wave >> 1;  // 0..3 (M)
  const int wc   = wave & 1;   // 0..1 (N)
  const int bn   = blockIdx.x; // 0..15
  const int bm   = blockIdx.y; // 0..15

  // ---- staging addresses: 512 thr x 16B = 64 rows x 128B per issue ----
  const int srow   = tid >> 3;
  const int schunk = (tid & 7) ^ (srow & 7);   // pre-swizzled global source
  const unsigned short* Ag[4];
  const unsigned short* Bg[2];
#pragma unroll
  for (int j = 0; j < 4; ++j)
    Ag[j] = A + (size_t)(bm * BM + j * 64 + srow) * K_DIM + schunk * 8;
#pragma unroll
  for (int j = 0; j < 2; ++j)
    Bg[j] = B + (size_t)(bn * BN + j * 64 + srow) * K_DIM + schunk * 8;

#define STAGE_ALL(buf, k0) do { \
    unsigned short* _da = &As[(buf) * A_TILE + tid * 8]; \
    unsigned short* _db = &Bs[(buf) * B_TILE + tid * 8]; \
    gload_lds16(Ag[0] + (k0), _da); \
    gload_lds16(Ag[1] + (k0), _da + 4096); \
    gload_lds16(Ag[2] + (k0), _da + 8192); \
    gload_lds16(Ag[3] + (k0), _da + 12288); \
    gload_lds16(Bg[0] + (k0), _db); \
    gload_lds16(Bg[1] + (k0), _db + 4096); \
  } while (0)

  // ---- ds_read offsets (elements): row (..+fr), k = kk*32 + qq*8.
  // Logical 16B chunk c = kk*4 + qq; swizzled slot = c ^ (fr&7).
  const int fr = lane & 15;
  const int qq = lane >> 4;
  const int xr = fr & 7;
  int aoff[4][2], boff[4][2];
#pragma unroll
  for (int mi = 0; mi < 4; ++mi)
#pragma unroll
    for (int kk = 0; kk < 2; ++kk)
      aoff[mi][kk] = ((wr * 64 + mi * 16 + fr) * 8 + ((kk * 4 + qq) ^ xr)) * 8;
#pragma unroll
  for (int ni = 0; ni < 4; ++ni)
#pragma unroll
    for (int kk = 0; kk < 2; ++kk)
      boff[ni][kk] = ((wc * 64 + ni * 16 + fr) * 8 + ((kk * 4 + qq) ^ xr)) * 8;

  const f32x4 z = {0.f, 0.f, 0.f, 0.f};
  f32x4 acc[4][4];
#pragma unroll
  for (int i = 0; i < 4; ++i)
#pragma unroll
    for (int j = 0; j < 4; ++j) acc[i][j] = z;

  // Two register subtile sets: A-phase regs (kk=0) and B-phase regs (kk=1).
  bf16x8 avA[4], bvA[4], avB[4], bvB[4];

#define READ_SET(av, bv, bufi, kk) do { \
    const unsigned short* Asb = &As[(bufi) * A_TILE]; \
    const unsigned short* Bsb = &Bs[(bufi) * B_TILE]; \
    bv[0] = LD8(Bsb + boff[0][kk]); bv[1] = LD8(Bsb + boff[1][kk]); \
    bv[2] = LD8(Bsb + boff[2][kk]); bv[3] = LD8(Bsb + boff[3][kk]); \
    av[0] = LD8(Asb + aoff[0][kk]); av[1] = LD8(Asb + aoff[1][kk]); \
    av[2] = LD8(Asb + aoff[2][kk]); av[3] = LD8(Asb + aoff[3][kk]); \
  } while (0)

#define MFMA_ALL(av, bv) do { \
    __builtin_amdgcn_s_setprio(1); \
    _Pragma("unroll") \
    for (int mi = 0; mi < 4; ++mi) { \
      acc[mi][0] = __builtin_amdgcn_mfma_f32_16x16x32_bf16(av[mi], bv[0], acc[mi][0], 0, 0, 0); \
      acc[mi][1] = __builtin_amdgcn_mfma_f32_16x16x32_bf16(av[mi], bv[1], acc[mi][1], 0, 0, 0); \
      acc[mi][2] = __builtin_amdgcn_mfma_f32_16x16x32_bf16(av[mi], bv[2], acc[mi][2], 0, 0, 0); \
      acc[mi][3] = __builtin_amdgcn_mfma_f32_16x16x32_bf16(av[mi], bv[3], acc[mi][3], 0, 0, 0); \
    } \
    __builtin_amdgcn_s_setprio(0); \
  } while (0)

  // One pipelined tile. bufi/stgbufi are LITERALS (buffer idx = t%3).
  // Phase A: stage(t+2), read B-regs(t) from buf[t], MFMA A-regs(t),
  //          vmcnt(6) [stage(t+1) landed], barrier.
  // Phase B: read A-regs(t+1) from buf[t+1], MFMA B-regs(t), barrier.
#define TILE_MAIN(bufi, stgbufi, stgt) do { \
    STAGE_ALL(stgbufi, (stgt) * BK); \
    READ_SET(avB, bvB, bufi, 1); \
    SCHED(); \
    MFMA_ALL(avA, bvA); \
    SCHED(); \
    VMWAIT(6); \
    SBAR(); \
    SCHED(); \
    READ_SET(avA, bvA, ((bufi) + 1) % 3, 0); \
    SCHED(); \
    MFMA_ALL(avB, bvB); \
    SBAR(); \
    SCHED(); \
  } while (0)

  // prologue: stage tiles 0,1; wait tile 0; pre-read A-regs(0).
  STAGE_ALL(0, 0);
  STAGE_ALL(1, BK);
  VMWAIT(6);
  SBAR();
  SCHED();
  READ_SET(avA, bvA, 0, 0);
  SCHED();

  // main loop: tiles 0..29, unrolled by 3 for literal buffer indices.
#pragma unroll 1
  for (int s = 0; s < 10; ++s) {
    const int t0 = s * 3;
    TILE_MAIN(0, 2, t0 + 2);
    TILE_MAIN(1, 0, t0 + 3);
    TILE_MAIN(2, 1, t0 + 4);
  }

  // ---- tail: tiles 30 (buf0) and 31 (buf1), no staging ----
  // t=30 phase A: read B-regs(30); MFMA A(30); vmcnt(0) [stage(31) landed].
  READ_SET(avB, bvB, 0, 1);
  SCHED();
  MFMA_ALL(avA, bvA);
  SCHED();
  VMWAIT(0);
  SBAR();
  SCHED();
  // t=30 phase B: read A-regs(31) from buf1; MFMA B(30).
  READ_SET(avA, bvA, 1, 0);
  SCHED();
  MFMA_ALL(avB, bvB);
  // t=31: buffer content static now, no barriers needed.
  READ_SET(avB, bvB, 1, 1);
  SCHED();
  MFMA_ALL(avA, bvA);
  MFMA_ALL(avB, bvB);

  // ---- epilogue: C/D layout col = lane&15, row = (lane>>4)*4 + r ----
  const int orow0 = bm * BM + wr * 64 + qq * 4;
  const int ocol0 = bn * BN + wc * 64 + fr;
#pragma unroll
  for (int ni = 0; ni < 4; ++ni) {
    const int col = ocol0 + ni * 16;
    const float bv = bias[col];
#pragma unroll
    for (int mi = 0; mi < 4; ++mi) {
      const int row = orow0 + mi * 16;
#pragma unroll
      for (int r = 0; r < 4; ++r)
        C[(size_t)(row + r) * N_DIM + col] = acc[mi][ni][r] + bv;
    }
  }
#undef TILE_MAIN
#undef MFMA_ALL
#undef READ_SET
#undef STAGE_ALL
}

// ---- safety fallback ----
__global__ __launch_bounds__(256) void gemm_f32_naive(
    const float* __restrict__ X, const float* __restrict__ W,
    const float* __restrict__ bias, float* __restrict__ C) {
  int o = blockIdx.x * 256 + threadIdx.x;
  if (o >= M_DIM * N_DIM) return;
  int m = o / N_DIM, n = o % N_DIM;
  const float* xr = X + (size_t)m * K_DIM;
  const float* wr = W + (size_t)n * K_DIM;
  float s = 0.f;
  for (int k = 0; k < K_DIM; ++k) s += xr[k] * wr[k];
  C[o] = s + bias[n];
}

extern "C" void kernel_launch(void* const* d_in, const int* in_sizes, int n_in,
                              void* d_out, int out_size, void* d_ws, size_t ws_size,
                              hipStream_t stream) {
  const float* x    = (const float*)d_in[0];
  const float* w    = (const float*)d_in[1];
  const float* bias = (const float*)d_in[2];
  float* out = (float*)d_out;

  const size_t x_elems = (size_t)M_DIM * K_DIM;
  const size_t w_elems = (size_t)N_DIM * K_DIM;
  const size_t need = (x_elems + w_elems) * sizeof(unsigned short);

  if (ws_size < need) {
    gemm_f32_naive<<<(M_DIM * N_DIM + 255) / 256, 256, 0, stream>>>(x, w, bias, out);
    return;
  }

  unsigned short* xb = (unsigned short*)d_ws;
  unsigned short* wb = xb + x_elems;

  const int xn8 = (int)(x_elems / 8);
  const int totn8 = (int)((x_elems + w_elems) / 8);
  cvt_both<<<(totn8 + 255) / 256, 256, 0, stream>>>(x, w, xb, xn8, totn8);

  dim3 grid(N_DIM / BN, M_DIM / BM);  // (16, 16) = 256 blocks, 1/CU
  gemm_8w<<<grid, 512, 0, stream>>>(xb, wb, bias, out);
}